// Round 1
// baseline (1043.908 us; speedup 1.0000x reference)
//
#include <hip/hip_runtime.h>
#include <math.h>

#define NVIEW 720
#define NDCT  1024
#define NZ    32
#define NX    512
#define NY    512

// Round fp32 -> bf16 bits (RNE). Inputs are finite random normals (no NaN/Inf).
__device__ __forceinline__ unsigned int f2bf_rne(float f) {
    unsigned int u = __float_as_uint(f);
    return (u + 0x7fffu + ((u >> 16) & 1u)) >> 16;
}

// packed[v][z][i] : lo16 = bf16(p[i]), hi16 = bf16(p[i+1]-p[i])
// Input x layout: (Z=32, 1, NVIEW=720, NDCT=1024), proj[v][z][i] = x[z][0][v][i].
__global__ __launch_bounds__(256) void pack_kernel(const float* __restrict__ x,
                                                   unsigned int* __restrict__ packed) {
    int tid = blockIdx.x * 256 + threadIdx.x;       // = (v*NZ + z)*NDCT + i
    if (tid >= NVIEW * NZ * NDCT) return;
    int i  = tid & (NDCT - 1);
    int vz = tid >> 10;                              // v*NZ + z
    int z  = vz & (NZ - 1);
    int v  = vz >> 5;
    const float* row = x + ((size_t)z * NVIEW + v) * NDCT;
    float p  = row[i];
    float pn = (i < NDCT - 1) ? row[i + 1] : 0.0f;   // never sampled (t<=873) but keep clean
    float d  = pn - p;
    packed[tid] = (f2bf_rne(d) << 16) | f2bf_rne(p);
}

// Main backprojection: block = 64x4 pixels, each thread owns one (x,y) pixel and
// all 32 z accumulators. i0/w computed once per (view,pixel), reused over z.
// t in [150.2, 872.8] -> no bounds checks (proved from geometry).
__global__ __launch_bounds__(256) void bp_packed(const unsigned int* __restrict__ packed,
                                                 float* __restrict__ out) {
    __shared__ float2 cs[NVIEW];
    int lt = threadIdx.y * 64 + threadIdx.x;
    for (int v = lt; v < NVIEW; v += 256) {
        float th = (float)v * (float)(M_PI / NVIEW);
        float s, c;
        sincosf(th, &s, &c);
        cs[v] = make_float2(c, s);
    }
    __syncthreads();

    int x = blockIdx.x * 64 + threadIdx.x;
    int y = blockIdx.y * 4 + threadIdx.y;
    float xf = (float)x - 255.5f;
    float yf = (float)y - 255.5f;

    float acc[NZ];
#pragma unroll
    for (int z = 0; z < NZ; ++z) acc[z] = 0.0f;

    for (int v = 0; v < NVIEW; ++v) {
        float2 a = cs[v];
        float t  = fmaf(xf, a.x, fmaf(yf, a.y, 511.5f));
        int   i0 = (int)t;            // t > 0 so trunc == floor
        float w  = t - (float)i0;
        const unsigned int* p = packed + ((size_t)v << 15) + i0;   // v*NZ*NDCT + i0
#pragma unroll
        for (int z = 0; z < NZ; ++z) {
            unsigned int u = p[(size_t)z << 10];                   // stride NDCT dwords
            float g0 = __uint_as_float(u << 16);
            float dd = __uint_as_float(u & 0xffff0000u);
            acc[z] += fmaf(w, dd, g0);
        }
    }

    const float scale = 0.0043633231299858236f;  // pi / 720
#pragma unroll
    for (int z = 0; z < NZ; ++z) {
        out[((size_t)z * NY + y) * NX + x] = acc[z] * scale;
    }
}

// Fallback (ws too small for packed array): direct fp32, two loads per sample.
__global__ __launch_bounds__(256) void bp_direct(const float* __restrict__ xin,
                                                 float* __restrict__ out) {
    __shared__ float2 cs[NVIEW];
    int lt = threadIdx.y * 64 + threadIdx.x;
    for (int v = lt; v < NVIEW; v += 256) {
        float th = (float)v * (float)(M_PI / NVIEW);
        float s, c;
        sincosf(th, &s, &c);
        cs[v] = make_float2(c, s);
    }
    __syncthreads();

    int x = blockIdx.x * 64 + threadIdx.x;
    int y = blockIdx.y * 4 + threadIdx.y;
    float xf = (float)x - 255.5f;
    float yf = (float)y - 255.5f;

    float acc[NZ];
#pragma unroll
    for (int z = 0; z < NZ; ++z) acc[z] = 0.0f;

    for (int v = 0; v < NVIEW; ++v) {
        float2 a = cs[v];
        float t  = fmaf(xf, a.x, fmaf(yf, a.y, 511.5f));
        int   i0 = (int)t;
        float w  = t - (float)i0;
        const float* p = xin + (size_t)v * NDCT + i0;   // x[z][0][v][i0], z via stride
#pragma unroll
        for (int z = 0; z < NZ; ++z) {
            float g0 = p[(size_t)z * NVIEW * NDCT];
            float g1 = p[(size_t)z * NVIEW * NDCT + 1];
            acc[z] += fmaf(w, g1 - g0, g0);
        }
    }

    const float scale = 0.0043633231299858236f;  // pi / 720
#pragma unroll
    for (int z = 0; z < NZ; ++z) {
        out[((size_t)z * NY + y) * NX + x] = acc[z] * scale;
    }
}

extern "C" void kernel_launch(void* const* d_in, const int* in_sizes, int n_in,
                              void* d_out, int out_size, void* d_ws, size_t ws_size,
                              hipStream_t stream) {
    const float* x = (const float*)d_in[0];
    float* out = (float*)d_out;

    const size_t packed_bytes = (size_t)NVIEW * NZ * NDCT * sizeof(unsigned int);  // 94.4 MB
    dim3 blk(64, 4);
    dim3 grd(NX / 64, NY / 4);

    if (ws_size >= packed_bytes) {
        unsigned int* packed = (unsigned int*)d_ws;
        int n = NVIEW * NZ * NDCT;
        pack_kernel<<<(n + 255) / 256, 256, 0, stream>>>(x, packed);
        bp_packed<<<grd, blk, 0, stream>>>(packed, out);
    } else {
        bp_direct<<<grd, blk, 0, stream>>>(x, out);
    }
}

// Round 2
// 1036.040 us; speedup vs baseline: 1.0076x; 1.0076x over previous
//
#include <hip/hip_runtime.h>
#include <math.h>

#define NVIEW 720
#define NDCT  1024
#define NZ    32
#define NX    512
#define NY    512

#define BX 16      // block tile x
#define BY 8       // block tile y
#define ZL 20      // z-slices served via LDS stage
#define NR 20      // detector rows staged per view (i0 spread <= 18 for 16x8 tile)

typedef unsigned int uint;

// Round fp32 -> bf16 bits (RNE). Inputs are finite random normals.
__device__ __forceinline__ uint f2bf_rne(float f) {
    uint u = __float_as_uint(f);
    return (u + 0x7fffu + ((u >> 16) & 1u)) >> 16;
}

// packed[v][i][z] : hi16 = bf16(g0=p[i]), lo16 = bf16(d=p[i+1]-p[i]); z contiguous.
// Consumer: g0(+junk<=2^-7) = as_float(u); d = as_float(u<<16).
// Input x layout: (Z=32, 1, NVIEW=720, NDCT=1024); proj[v][z][i] = x[z][0][v][i].
__global__ __launch_bounds__(64) void pack_kernel(const float* __restrict__ x,
                                                  uint* __restrict__ packed) {
    int v = blockIdx.x;                       // 0..719
    int i = blockIdx.y * 64 + threadIdx.x;    // 0..1023, lane-contiguous (coalesced reads)
    const float* base = x + (size_t)v * NDCT + i;     // + z * NVIEW*NDCT
    uint* o = packed + (((size_t)v * NDCT + i) << 5); // 32 dwords per (v,i) row
    #pragma unroll
    for (int zb = 0; zb < 8; ++zb) {
        uint4 u4;
        uint w[4];
        #pragma unroll
        for (int j = 0; j < 4; ++j) {
            int z = zb * 4 + j;
            float g0 = base[(size_t)z * NVIEW * NDCT];
            float g1 = (i < NDCT - 1) ? base[(size_t)z * NVIEW * NDCT + 1] : 0.0f;
            w[j] = (f2bf_rne(g0) << 16) | f2bf_rne(g1 - g0);
        }
        u4.x = w[0]; u4.y = w[1]; u4.z = w[2]; u4.w = w[3];
        *(uint4*)(o + zb * 4) = u4;
    }
}

// 2 ALU-light ops + 1 lshl per sample:
//   acc += as_float(u)            (g0 with <=2^-7 relative junk from d's bits)
//   acc  = fma(w, as_float(u<<16), acc)
#define SAMPLE(zz, uu) do { \
    acc[zz] += __uint_as_float(uu); \
    acc[zz]  = fmaf(w, __uint_as_float((uu) << 16), acc[zz]); \
} while (0)

__global__ __launch_bounds__(128, 4) void bp_hybrid(const uint* __restrict__ packed,
                                                    float* __restrict__ out) {
    __shared__ __align__(16) uint stage[NR * ZL];   // 400 dwords; row stride 20 dw = 80 B (16B-aligned)
    __shared__ float2 cs[NVIEW];
    __shared__ int imintab[NVIEW];

    const int tid = threadIdx.y * BX + threadIdx.x;   // 0..127
    const float xf0 = (float)(int)(blockIdx.x * BX) - 255.5f;
    const float yf0 = (float)(int)(blockIdx.y * BY) - 255.5f;

    // Per-view cos/sin + block-uniform imin (exact lower bound: corner minima computed
    // with the same fmaf structure as the per-thread t; fmaf is monotone per-operand).
    for (int v = tid; v < NVIEW; v += BX * BY) {
        float th = (float)v * (float)(M_PI / NVIEW);
        float s, c;
        sincosf(th, &s, &c);
        cs[v] = make_float2(c, s);
        float b0 = fmaf(yf0, s, 511.5f);
        float b1 = fmaf(yf0 + (float)(BY - 1), s, 511.5f);
        float t00 = fmaf(xf0, c, b0);
        float t10 = fmaf(xf0 + (float)(BX - 1), c, b0);
        float t01 = fmaf(xf0, c, b1);
        float t11 = fmaf(xf0 + (float)(BX - 1), c, b1);
        float tmin = fminf(fminf(t00, t10), fminf(t01, t11));
        imintab[v] = (int)tmin;   // t in [150, 873] -> trunc == floor
    }
    __syncthreads();

    const int x = blockIdx.x * BX + threadIdx.x;
    const int y = blockIdx.y * BY + threadIdx.y;
    const float xf = (float)x - 255.5f;
    const float yf = (float)y - 255.5f;

    float acc[NZ];
    #pragma unroll
    for (int z = 0; z < NZ; ++z) acc[z] = 0.0f;

    // Staging roles: 100 threads move NR=20 rows x ZL=20 dwords as dwordx4.
    const int  sr   = tid / 5;           // staged row 0..19
    const int  sk   = (tid % 5) * 4;     // dword col 0,4,8,12,16
    const bool sact = (tid < NR * 5);

    uint4 st;
    if (sact) {
        const uint* g = packed + (((uint)imintab[0] + sr) << 5) + sk;
        st = *(const uint4*)g;
    }

    for (int v = 0; v < NVIEW; ++v) {
        __syncthreads();                                   // readers of view v-1 done
        if (sact) *(uint4*)&stage[sr * ZL + sk] = st;      // publish view v (z<ZL, rows imin..imin+19)
        __syncthreads();
        if (sact && v + 1 < NVIEW) {                       // prefetch view v+1; latency hidden by compute
            const uint* g = packed + ((size_t)(v + 1) << 15) + (((uint)imintab[v + 1] + sr) << 5) + sk;
            st = *(const uint4*)g;
        }

        float2 a = cs[v];
        float t  = fmaf(xf, a.x, fmaf(yf, a.y, 511.5f));
        int   i0 = (int)t;
        float w  = t - (float)i0;
        int   rl = i0 - imintab[v];
        rl = max(0, min(rl, NR - 1));                      // belt-and-braces; should never clamp

        // z in [0, ZL): from LDS
        const uint* sp = &stage[rl * ZL];
        #pragma unroll
        for (int j = 0; j < 5; ++j) {
            uint4 q = *(const uint4*)(sp + j * 4);
            SAMPLE(j * 4 + 0, q.x);
            SAMPLE(j * 4 + 1, q.y);
            SAMPLE(j * 4 + 2, q.z);
            SAMPLE(j * 4 + 3, q.w);
        }
        // z in [ZL, 32): direct from global (L1 path; all 3 loads hit one 64B line per row)
        const uint* gp = packed + ((size_t)v << 15) + ((uint)i0 << 5) + ZL;
        uint4 q5 = *(const uint4*)(gp);
        uint4 q6 = *(const uint4*)(gp + 4);
        uint4 q7 = *(const uint4*)(gp + 8);
        SAMPLE(20, q5.x); SAMPLE(21, q5.y); SAMPLE(22, q5.z); SAMPLE(23, q5.w);
        SAMPLE(24, q6.x); SAMPLE(25, q6.y); SAMPLE(26, q6.z); SAMPLE(27, q6.w);
        SAMPLE(28, q7.x); SAMPLE(29, q7.y); SAMPLE(30, q7.z); SAMPLE(31, q7.w);
    }

    const float scale = 0.0043633231299858236f;  // pi / 720
    #pragma unroll
    for (int z = 0; z < NZ; ++z) {
        out[((size_t)z * NY + y) * NX + x] = acc[z] * scale;
    }
}

// Fallback (ws too small for packed array): direct fp32, two loads per sample.
__global__ __launch_bounds__(256) void bp_direct(const float* __restrict__ xin,
                                                 float* __restrict__ out) {
    __shared__ float2 cs[NVIEW];
    int lt = threadIdx.y * 64 + threadIdx.x;
    for (int v = lt; v < NVIEW; v += 256) {
        float th = (float)v * (float)(M_PI / NVIEW);
        float s, c;
        sincosf(th, &s, &c);
        cs[v] = make_float2(c, s);
    }
    __syncthreads();

    int x = blockIdx.x * 64 + threadIdx.x;
    int y = blockIdx.y * 4 + threadIdx.y;
    float xf = (float)x - 255.5f;
    float yf = (float)y - 255.5f;

    float acc[NZ];
    #pragma unroll
    for (int z = 0; z < NZ; ++z) acc[z] = 0.0f;

    for (int v = 0; v < NVIEW; ++v) {
        float2 a = cs[v];
        float t  = fmaf(xf, a.x, fmaf(yf, a.y, 511.5f));
        int   i0 = (int)t;
        float w  = t - (float)i0;
        const float* p = xin + (size_t)v * NDCT + i0;
        #pragma unroll
        for (int z = 0; z < NZ; ++z) {
            float g0 = p[(size_t)z * NVIEW * NDCT];
            float g1 = p[(size_t)z * NVIEW * NDCT + 1];
            acc[z] += fmaf(w, g1 - g0, g0);
        }
    }

    const float scale = 0.0043633231299858236f;
    #pragma unroll
    for (int z = 0; z < NZ; ++z) {
        out[((size_t)z * NY + y) * NX + x] = acc[z] * scale;
    }
}

extern "C" void kernel_launch(void* const* d_in, const int* in_sizes, int n_in,
                              void* d_out, int out_size, void* d_ws, size_t ws_size,
                              hipStream_t stream) {
    const float* x = (const float*)d_in[0];
    float* out = (float*)d_out;

    const size_t packed_bytes = (size_t)NVIEW * NDCT * NZ * sizeof(uint);  // 94.4 MB

    if (ws_size >= packed_bytes) {
        uint* packed = (uint*)d_ws;
        pack_kernel<<<dim3(NVIEW, NDCT / 64), 64, 0, stream>>>(x, packed);
        bp_hybrid<<<dim3(NX / BX, NY / BY), dim3(BX, BY), 0, stream>>>(packed, out);
    } else {
        bp_direct<<<dim3(NX / 64, NY / 4), dim3(64, 4), 0, stream>>>(x, out);
    }
}